// Round 1
// baseline (212.590 us; speedup 1.0000x reference)
//
#include <hip/hip_runtime.h>

#define NV 100000
#define NJ 24
#define NP 207

// ---------------------------------------------------------------------------
// K1: v_shaped = v_template + shapedirs @ betas   (written into d_out buffer)
// ---------------------------------------------------------------------------
__global__ __launch_bounds__(256) void k_shape(
    const float* __restrict__ betas, const float* __restrict__ v_template,
    const float* __restrict__ shapedirs, float* __restrict__ v_shaped) {
  __shared__ float sb[10];
  int tid = threadIdx.x;
  if (tid < 10) sb[tid] = betas[tid];
  __syncthreads();
  int v = blockIdx.x * 256 + tid;
  if (v >= NV) return;
  const float* sd = shapedirs + (size_t)v * 30;
  #pragma unroll
  for (int k = 0; k < 3; ++k) {
    float a = v_template[v * 3 + k];
    #pragma unroll
    for (int s = 0; s < 10; ++s) a += sd[k * 10 + s] * sb[s];
    v_shaped[v * 3 + k] = a;
  }
}

// ---------------------------------------------------------------------------
// K2: J partials.  grid = (24 joints, 4 parts).  jpart[(part*24+j)*3+k]
// ---------------------------------------------------------------------------
__global__ __launch_bounds__(256) void k_jreg(
    const float* __restrict__ Jreg, const float* __restrict__ v_shaped,
    float* __restrict__ jpart) {
  int j = blockIdx.x;
  int part = blockIdx.y;
  int tid = threadIdx.x;
  int v0 = part * (NV / 4);
  int v1 = v0 + (NV / 4);
  float s0 = 0.f, s1 = 0.f, s2 = 0.f;
  for (int v = v0 + tid; v < v1; v += 256) {
    float w = Jreg[(size_t)j * NV + v];
    s0 += w * v_shaped[v * 3 + 0];
    s1 += w * v_shaped[v * 3 + 1];
    s2 += w * v_shaped[v * 3 + 2];
  }
  __shared__ float red[256][3];
  red[tid][0] = s0; red[tid][1] = s1; red[tid][2] = s2;
  __syncthreads();
  for (int off = 128; off > 0; off >>= 1) {
    if (tid < off) {
      red[tid][0] += red[tid + off][0];
      red[tid][1] += red[tid + off][1];
      red[tid][2] += red[tid + off][2];
    }
    __syncthreads();
  }
  if (tid < 3) jpart[(part * NJ + j) * 3 + tid] = red[0][tid];
}

// ---------------------------------------------------------------------------
// K3: single block: finalize J, rodrigues, FK chain, rel matrices, lrotmin
// ---------------------------------------------------------------------------
__global__ __launch_bounds__(64) void k_fk(
    const float* __restrict__ pose, const float* __restrict__ jpart,
    float* __restrict__ lrot, float* __restrict__ rel) {
  __shared__ float J[NJ][3];
  __shared__ float R[NJ][9];
  __shared__ float G[NJ][12];  // rows 0..2 of 4x4, [a*4+b], col3 = translation
  int tid = threadIdx.x;
  if (tid < NJ) {
    for (int k = 0; k < 3; ++k) {
      float a = 0.f;
      for (int part = 0; part < 4; ++part) a += jpart[(part * NJ + tid) * 3 + k];
      J[tid][k] = a;
    }
    float rx = pose[tid * 3 + 0], ry = pose[tid * 3 + 1], rz = pose[tid * 3 + 2];
    float tx = rx + 1e-8f, ty = ry + 1e-8f, tz = rz + 1e-8f;
    float theta = sqrtf(tx * tx + ty * ty + tz * tz);
    float x = rx / theta, y = ry / theta, z = rz / theta;
    float c = cosf(theta), s = sinf(theta), C = 1.f - c;
    float* Rr = R[tid];
    Rr[0] = c + C * x * x;     Rr[1] = C * x * y - s * z; Rr[2] = C * x * z + s * y;
    Rr[3] = C * x * y + s * z; Rr[4] = c + C * y * y;     Rr[5] = C * y * z - s * x;
    Rr[6] = C * x * z - s * y; Rr[7] = C * y * z + s * x; Rr[8] = c + C * z * z;
    if (tid >= 1) {
      #pragma unroll
      for (int e = 0; e < 9; ++e) {
        float id = (e == 0 || e == 4 || e == 8) ? 1.f : 0.f;
        lrot[(tid - 1) * 9 + e] = Rr[e] - id;
      }
    }
  }
  __syncthreads();
  if (tid == 0) {
    const int par[NJ] = {-1,0,0,0,1,2,3,4,5,6,7,8,9,9,9,12,13,14,16,17,18,19,20,21};
    for (int a = 0; a < 3; ++a) {
      for (int b = 0; b < 3; ++b) G[0][a * 4 + b] = R[0][a * 3 + b];
      G[0][a * 4 + 3] = J[0][a];
    }
    for (int i = 1; i < NJ; ++i) {
      int p = par[i];
      float t0 = J[i][0] - J[p][0], t1 = J[i][1] - J[p][1], t2 = J[i][2] - J[p][2];
      for (int a = 0; a < 3; ++a) {
        float g0 = G[p][a * 4 + 0], g1 = G[p][a * 4 + 1], g2 = G[p][a * 4 + 2];
        for (int b = 0; b < 3; ++b)
          G[i][a * 4 + b] = g0 * R[i][0 * 3 + b] + g1 * R[i][1 * 3 + b] + g2 * R[i][2 * 3 + b];
        G[i][a * 4 + 3] = G[p][a * 4 + 3] + g0 * t0 + g1 * t1 + g2 * t2;
      }
    }
  }
  __syncthreads();
  if (tid < NJ) {
    for (int a = 0; a < 3; ++a) {
      float corr = G[tid][a * 4 + 0] * J[tid][0] + G[tid][a * 4 + 1] * J[tid][1] +
                   G[tid][a * 4 + 2] * J[tid][2];
      rel[tid * 12 + a * 4 + 0] = G[tid][a * 4 + 0];
      rel[tid * 12 + a * 4 + 1] = G[tid][a * 4 + 1];
      rel[tid * 12 + a * 4 + 2] = G[tid][a * 4 + 2];
      rel[tid * 12 + a * 4 + 3] = G[tid][a * 4 + 3] - corr;
    }
  }
}

// ---------------------------------------------------------------------------
// K4: v_posed = v_shaped + posedirs @ lrotmin; LBS; scale+trans.
// Reads v_shaped from vbuf, overwrites vbuf with final verts (per-thread safe).
// ---------------------------------------------------------------------------
__global__ __launch_bounds__(256) void k_lbs(
    const float* __restrict__ posedirs, const float* __restrict__ weights,
    const float* __restrict__ lrot, const float* __restrict__ rel,
    const float* __restrict__ scale, const float* __restrict__ trans,
    float* __restrict__ vbuf) {
  __shared__ float lr[NP];
  __shared__ float rl[NJ * 12];
  int tid = threadIdx.x;
  if (tid < NP) lr[tid] = lrot[tid];
  for (int i = tid; i < NJ * 12; i += 256) rl[i] = rel[i];
  __syncthreads();
  int v = blockIdx.x * 256 + tid;
  if (v >= NV) return;
  float a0 = vbuf[v * 3 + 0], a1 = vbuf[v * 3 + 1], a2 = vbuf[v * 3 + 2];
  const float* pd = posedirs + (size_t)v * (3 * NP);
  for (int p = 0; p < NP; ++p) {
    float l = lr[p];
    a0 += pd[p] * l;
    a1 += pd[NP + p] * l;
    a2 += pd[2 * NP + p] * l;
  }
  const float* wv = weights + (size_t)v * NJ;
  float T[12];
  #pragma unroll
  for (int e = 0; e < 12; ++e) T[e] = 0.f;
  for (int j = 0; j < NJ; ++j) {
    float w = wv[j];
    #pragma unroll
    for (int e = 0; e < 12; ++e) T[e] += w * rl[j * 12 + e];
  }
  float sc = scale[0];
  float o0 = T[0] * a0 + T[1] * a1 + T[2]  * a2 + T[3];
  float o1 = T[4] * a0 + T[5] * a1 + T[6]  * a2 + T[7];
  float o2 = T[8] * a0 + T[9] * a1 + T[10] * a2 + T[11];
  vbuf[v * 3 + 0] = o0 * sc + trans[0];
  vbuf[v * 3 + 1] = o1 * sc + trans[1];
  vbuf[v * 3 + 2] = o2 * sc + trans[2];
}

extern "C" void kernel_launch(void* const* d_in, const int* in_sizes, int n_in,
                              void* d_out, int out_size, void* d_ws, size_t ws_size,
                              hipStream_t stream) {
  const float* betas      = (const float*)d_in[0];
  const float* pose       = (const float*)d_in[1];
  const float* scale      = (const float*)d_in[2];
  const float* trans      = (const float*)d_in[3];
  const float* v_template = (const float*)d_in[4];
  const float* shapedirs  = (const float*)d_in[5];
  const float* posedirs   = (const float*)d_in[6];
  const float* Jreg       = (const float*)d_in[7];
  const float* weights    = (const float*)d_in[8];
  float* out = (float*)d_out;
  float* ws  = (float*)d_ws;

  float* jpart = ws;        // 288 floats
  float* lrot  = ws + 288;  // 207 floats
  float* rel   = ws + 512;  // 288 floats

  int blocks = (NV + 255) / 256;
  k_shape<<<blocks, 256, 0, stream>>>(betas, v_template, shapedirs, out);
  k_jreg<<<dim3(NJ, 4), 256, 0, stream>>>(Jreg, out, jpart);
  k_fk<<<1, 64, 0, stream>>>(pose, jpart, lrot, rel);
  k_lbs<<<blocks, 256, 0, stream>>>(posedirs, weights, lrot, rel, scale, trans, out);
}

// Round 2
// 109.797 us; speedup vs baseline: 1.9362x; 1.9362x over previous
//
#include <hip/hip_runtime.h>

#define NV 100000
#define NJ 24
#define NP 207

// ---------------------------------------------------------------------------
// K1: v_shaped = v_template + shapedirs @ betas   (written into d_out buffer)
// ---------------------------------------------------------------------------
__global__ __launch_bounds__(256) void k_shape(
    const float* __restrict__ betas, const float* __restrict__ v_template,
    const float* __restrict__ shapedirs, float* __restrict__ v_shaped) {
  __shared__ float sb[10];
  int tid = threadIdx.x;
  if (tid < 10) sb[tid] = betas[tid];
  __syncthreads();
  int v = blockIdx.x * 256 + tid;
  if (v >= NV) return;
  const float* sd = shapedirs + (size_t)v * 30;
  #pragma unroll
  for (int k = 0; k < 3; ++k) {
    float a = v_template[v * 3 + k];
    #pragma unroll
    for (int s = 0; s < 10; ++s) a += sd[k * 10 + s] * sb[s];
    v_shaped[v * 3 + k] = a;
  }
}

// ---------------------------------------------------------------------------
// K2: J partials.  grid = (24 joints, 4 parts).  jpart[(part*24+j)*3+k]
// ---------------------------------------------------------------------------
__global__ __launch_bounds__(256) void k_jreg(
    const float* __restrict__ Jreg, const float* __restrict__ v_shaped,
    float* __restrict__ jpart) {
  int j = blockIdx.x;
  int part = blockIdx.y;
  int tid = threadIdx.x;
  int v0 = part * (NV / 4);
  int v1 = v0 + (NV / 4);
  float s0 = 0.f, s1 = 0.f, s2 = 0.f;
  for (int v = v0 + tid; v < v1; v += 256) {
    float w = Jreg[(size_t)j * NV + v];
    s0 += w * v_shaped[v * 3 + 0];
    s1 += w * v_shaped[v * 3 + 1];
    s2 += w * v_shaped[v * 3 + 2];
  }
  __shared__ float red[256][3];
  red[tid][0] = s0; red[tid][1] = s1; red[tid][2] = s2;
  __syncthreads();
  for (int off = 128; off > 0; off >>= 1) {
    if (tid < off) {
      red[tid][0] += red[tid + off][0];
      red[tid][1] += red[tid + off][1];
      red[tid][2] += red[tid + off][2];
    }
    __syncthreads();
  }
  if (tid < 3) jpart[(part * NJ + j) * 3 + tid] = red[0][tid];
}

// ---------------------------------------------------------------------------
// K3: single block: finalize J, rodrigues, FK chain, rel matrices, lrotmin
// ---------------------------------------------------------------------------
__global__ __launch_bounds__(64) void k_fk(
    const float* __restrict__ pose, const float* __restrict__ jpart,
    float* __restrict__ lrot, float* __restrict__ rel) {
  __shared__ float J[NJ][3];
  __shared__ float R[NJ][9];
  __shared__ float G[NJ][12];  // rows 0..2 of 4x4, [a*4+b], col3 = translation
  int tid = threadIdx.x;
  if (tid < NJ) {
    for (int k = 0; k < 3; ++k) {
      float a = 0.f;
      for (int part = 0; part < 4; ++part) a += jpart[(part * NJ + tid) * 3 + k];
      J[tid][k] = a;
    }
    float rx = pose[tid * 3 + 0], ry = pose[tid * 3 + 1], rz = pose[tid * 3 + 2];
    float tx = rx + 1e-8f, ty = ry + 1e-8f, tz = rz + 1e-8f;
    float theta = sqrtf(tx * tx + ty * ty + tz * tz);
    float x = rx / theta, y = ry / theta, z = rz / theta;
    float c = cosf(theta), s = sinf(theta), C = 1.f - c;
    float* Rr = R[tid];
    Rr[0] = c + C * x * x;     Rr[1] = C * x * y - s * z; Rr[2] = C * x * z + s * y;
    Rr[3] = C * x * y + s * z; Rr[4] = c + C * y * y;     Rr[5] = C * y * z - s * x;
    Rr[6] = C * x * z - s * y; Rr[7] = C * y * z + s * x; Rr[8] = c + C * z * z;
    if (tid >= 1) {
      #pragma unroll
      for (int e = 0; e < 9; ++e) {
        float id = (e == 0 || e == 4 || e == 8) ? 1.f : 0.f;
        lrot[(tid - 1) * 9 + e] = Rr[e] - id;
      }
    }
  }
  __syncthreads();
  if (tid == 0) {
    const int par[NJ] = {-1,0,0,0,1,2,3,4,5,6,7,8,9,9,9,12,13,14,16,17,18,19,20,21};
    for (int a = 0; a < 3; ++a) {
      for (int b = 0; b < 3; ++b) G[0][a * 4 + b] = R[0][a * 3 + b];
      G[0][a * 4 + 3] = J[0][a];
    }
    for (int i = 1; i < NJ; ++i) {
      int p = par[i];
      float t0 = J[i][0] - J[p][0], t1 = J[i][1] - J[p][1], t2 = J[i][2] - J[p][2];
      for (int a = 0; a < 3; ++a) {
        float g0 = G[p][a * 4 + 0], g1 = G[p][a * 4 + 1], g2 = G[p][a * 4 + 2];
        for (int b = 0; b < 3; ++b)
          G[i][a * 4 + b] = g0 * R[i][0 * 3 + b] + g1 * R[i][1 * 3 + b] + g2 * R[i][2 * 3 + b];
        G[i][a * 4 + 3] = G[p][a * 4 + 3] + g0 * t0 + g1 * t1 + g2 * t2;
      }
    }
  }
  __syncthreads();
  if (tid < NJ) {
    for (int a = 0; a < 3; ++a) {
      float corr = G[tid][a * 4 + 0] * J[tid][0] + G[tid][a * 4 + 1] * J[tid][1] +
                   G[tid][a * 4 + 2] * J[tid][2];
      rel[tid * 12 + a * 4 + 0] = G[tid][a * 4 + 0];
      rel[tid * 12 + a * 4 + 1] = G[tid][a * 4 + 1];
      rel[tid * 12 + a * 4 + 2] = G[tid][a * 4 + 2];
      rel[tid * 12 + a * 4 + 3] = G[tid][a * 4 + 3] - corr;
    }
  }
}

// ---------------------------------------------------------------------------
// K4a: pose blend, one WAVE per vertex. Lanes read the vertex's 621 contiguous
// floats lane-strided (coalesced 256B/instr), dot with lrotmin from LDS,
// butterfly-reduce 3 sums, lane 0 does vbuf[v] += delta  (vbuf = v_shaped).
// ---------------------------------------------------------------------------
__global__ __launch_bounds__(256) void k_pose(
    const float* __restrict__ posedirs, const float* __restrict__ lrot,
    float* __restrict__ vbuf) {
  __shared__ float lr[NP];
  int tid = threadIdx.x;
  if (tid < NP) lr[tid] = lrot[tid];
  __syncthreads();
  int wave = tid >> 6, lane = tid & 63;
  int v = blockIdx.x * 4 + wave;
  if (v >= NV) return;
  const float* pd = posedirs + (size_t)v * (3 * NP);
  float acc0 = 0.f, acc1 = 0.f, acc2 = 0.f;
  #pragma unroll
  for (int i = 0; i < 10; ++i) {
    int e = lane + i * 64;
    if (e < 3 * NP) {
      float x = pd[e];
      int k = (e >= NP) + (e >= 2 * NP);
      int p = e - k * NP;
      float prod = x * lr[p];
      if (k == 0) acc0 += prod;
      else if (k == 1) acc1 += prod;
      else acc2 += prod;
    }
  }
  #pragma unroll
  for (int off = 32; off > 0; off >>= 1) {
    acc0 += __shfl_xor(acc0, off);
    acc1 += __shfl_xor(acc1, off);
    acc2 += __shfl_xor(acc2, off);
  }
  if (lane == 0) {
    vbuf[v * 3 + 0] += acc0;
    vbuf[v * 3 + 1] += acc1;
    vbuf[v * 3 + 2] += acc2;
  }
}

// ---------------------------------------------------------------------------
// K4b: LBS + scale/trans. weights via float4 (96B rows are 16B-aligned),
// rel broadcast from LDS. Reads v_posed from vbuf, writes final verts.
// ---------------------------------------------------------------------------
__global__ __launch_bounds__(256) void k_lbs2(
    const float* __restrict__ weights, const float* __restrict__ rel,
    const float* __restrict__ scale, const float* __restrict__ trans,
    float* __restrict__ vbuf) {
  __shared__ float rl[NJ * 12];
  int tid = threadIdx.x;
  for (int i = tid; i < NJ * 12; i += 256) rl[i] = rel[i];
  __syncthreads();
  int v = blockIdx.x * 256 + tid;
  if (v >= NV) return;
  float a0 = vbuf[v * 3 + 0], a1 = vbuf[v * 3 + 1], a2 = vbuf[v * 3 + 2];
  float4 w4[6];
  const float4* wv = (const float4*)(weights + (size_t)v * NJ);
  #pragma unroll
  for (int i = 0; i < 6; ++i) w4[i] = wv[i];
  const float* w = (const float*)w4;
  float T[12];
  #pragma unroll
  for (int e = 0; e < 12; ++e) T[e] = 0.f;
  #pragma unroll
  for (int j = 0; j < NJ; ++j) {
    float wj = w[j];
    #pragma unroll
    for (int e = 0; e < 12; ++e) T[e] += wj * rl[j * 12 + e];
  }
  float sc = scale[0];
  float o0 = T[0] * a0 + T[1] * a1 + T[2]  * a2 + T[3];
  float o1 = T[4] * a0 + T[5] * a1 + T[6]  * a2 + T[7];
  float o2 = T[8] * a0 + T[9] * a1 + T[10] * a2 + T[11];
  vbuf[v * 3 + 0] = o0 * sc + trans[0];
  vbuf[v * 3 + 1] = o1 * sc + trans[1];
  vbuf[v * 3 + 2] = o2 * sc + trans[2];
}

extern "C" void kernel_launch(void* const* d_in, const int* in_sizes, int n_in,
                              void* d_out, int out_size, void* d_ws, size_t ws_size,
                              hipStream_t stream) {
  const float* betas      = (const float*)d_in[0];
  const float* pose       = (const float*)d_in[1];
  const float* scale      = (const float*)d_in[2];
  const float* trans      = (const float*)d_in[3];
  const float* v_template = (const float*)d_in[4];
  const float* shapedirs  = (const float*)d_in[5];
  const float* posedirs   = (const float*)d_in[6];
  const float* Jreg       = (const float*)d_in[7];
  const float* weights    = (const float*)d_in[8];
  float* out = (float*)d_out;
  float* ws  = (float*)d_ws;

  float* jpart = ws;        // 288 floats
  float* lrot  = ws + 288;  // 207 floats
  float* rel   = ws + 512;  // 288 floats

  int blocks = (NV + 255) / 256;
  k_shape<<<blocks, 256, 0, stream>>>(betas, v_template, shapedirs, out);
  k_jreg<<<dim3(NJ, 4), 256, 0, stream>>>(Jreg, out, jpart);
  k_fk<<<1, 64, 0, stream>>>(pose, jpart, lrot, rel);
  k_pose<<<NV / 4, 256, 0, stream>>>(posedirs, lrot, out);
  k_lbs2<<<blocks, 256, 0, stream>>>(weights, rel, scale, trans, out);
}

// Round 3
// 80.523 us; speedup vs baseline: 2.6401x; 1.3636x over previous
//
#include <hip/hip_runtime.h>

#define NV 100000
#define NJ 24
#define NP 207
#define NPART 16
#define VPB 16                 // vertices per block in k_pose
#define ROWF (3 * NP)          // 621 floats per vertex row
#define TILEF (VPB * ROWF)     // 9936 floats per block tile
#define TILE4 (TILEF / 4)      // 2484 float4 per tile

// ---------------------------------------------------------------------------
// K1: v_shaped = v_template + shapedirs @ betas, flat over 300000 rows of 10.
// ---------------------------------------------------------------------------
__global__ __launch_bounds__(256) void k_shape(
    const float* __restrict__ betas, const float* __restrict__ v_template,
    const float* __restrict__ shapedirs, float* __restrict__ v_shaped) {
  __shared__ float sb[10];
  if (threadIdx.x < 10) sb[threadIdx.x] = betas[threadIdx.x];
  __syncthreads();
  int R = blockIdx.x * 256 + threadIdx.x;
  if (R >= 3 * NV) return;
  const float2* sd = (const float2*)(shapedirs + (size_t)R * 10);
  float a = v_template[R];
  #pragma unroll
  for (int s = 0; s < 5; ++s) {
    float2 x = sd[s];
    a += x.x * sb[2 * s] + x.y * sb[2 * s + 1];
  }
  v_shaped[R] = a;
}

// ---------------------------------------------------------------------------
// K2: J partials.  grid = (24 joints, NPART parts).
// ---------------------------------------------------------------------------
__global__ __launch_bounds__(256) void k_jreg(
    const float* __restrict__ Jreg, const float* __restrict__ v_shaped,
    float* __restrict__ jpart) {
  int j = blockIdx.x;
  int part = blockIdx.y;
  int tid = threadIdx.x;
  int v0 = part * (NV / NPART);
  int v1 = v0 + (NV / NPART);
  float s0 = 0.f, s1 = 0.f, s2 = 0.f;
  for (int v = v0 + tid; v < v1; v += 256) {
    float w = Jreg[(size_t)j * NV + v];
    s0 += w * v_shaped[v * 3 + 0];
    s1 += w * v_shaped[v * 3 + 1];
    s2 += w * v_shaped[v * 3 + 2];
  }
  __shared__ float red[256][3];
  red[tid][0] = s0; red[tid][1] = s1; red[tid][2] = s2;
  __syncthreads();
  for (int off = 128; off > 0; off >>= 1) {
    if (tid < off) {
      red[tid][0] += red[tid + off][0];
      red[tid][1] += red[tid + off][1];
      red[tid][2] += red[tid + off][2];
    }
    __syncthreads();
  }
  if (tid < 3) jpart[(part * NJ + j) * 3 + tid] = red[0][tid];
}

// ---------------------------------------------------------------------------
// K3: single block: finalize J, rodrigues, FK chain, rel matrices, lrotmin
// ---------------------------------------------------------------------------
__global__ __launch_bounds__(64) void k_fk(
    const float* __restrict__ pose, const float* __restrict__ jpart,
    float* __restrict__ lrot, float* __restrict__ rel) {
  __shared__ float J[NJ][3];
  __shared__ float R[NJ][9];
  __shared__ float G[NJ][12];
  int tid = threadIdx.x;
  if (tid < NJ) {
    for (int k = 0; k < 3; ++k) {
      float a = 0.f;
      for (int part = 0; part < NPART; ++part) a += jpart[(part * NJ + tid) * 3 + k];
      J[tid][k] = a;
    }
    float rx = pose[tid * 3 + 0], ry = pose[tid * 3 + 1], rz = pose[tid * 3 + 2];
    float tx = rx + 1e-8f, ty = ry + 1e-8f, tz = rz + 1e-8f;
    float theta = sqrtf(tx * tx + ty * ty + tz * tz);
    float x = rx / theta, y = ry / theta, z = rz / theta;
    float c = cosf(theta), s = sinf(theta), C = 1.f - c;
    float* Rr = R[tid];
    Rr[0] = c + C * x * x;     Rr[1] = C * x * y - s * z; Rr[2] = C * x * z + s * y;
    Rr[3] = C * x * y + s * z; Rr[4] = c + C * y * y;     Rr[5] = C * y * z - s * x;
    Rr[6] = C * x * z - s * y; Rr[7] = C * y * z + s * x; Rr[8] = c + C * z * z;
    if (tid >= 1) {
      #pragma unroll
      for (int e = 0; e < 9; ++e) {
        float id = (e == 0 || e == 4 || e == 8) ? 1.f : 0.f;
        lrot[(tid - 1) * 9 + e] = Rr[e] - id;
      }
    }
  }
  __syncthreads();
  if (tid == 0) {
    const int par[NJ] = {-1,0,0,0,1,2,3,4,5,6,7,8,9,9,9,12,13,14,16,17,18,19,20,21};
    for (int a = 0; a < 3; ++a) {
      for (int b = 0; b < 3; ++b) G[0][a * 4 + b] = R[0][a * 3 + b];
      G[0][a * 4 + 3] = J[0][a];
    }
    for (int i = 1; i < NJ; ++i) {
      int p = par[i];
      float t0 = J[i][0] - J[p][0], t1 = J[i][1] - J[p][1], t2 = J[i][2] - J[p][2];
      for (int a = 0; a < 3; ++a) {
        float g0 = G[p][a * 4 + 0], g1 = G[p][a * 4 + 1], g2 = G[p][a * 4 + 2];
        for (int b = 0; b < 3; ++b)
          G[i][a * 4 + b] = g0 * R[i][0 * 3 + b] + g1 * R[i][1 * 3 + b] + g2 * R[i][2 * 3 + b];
        G[i][a * 4 + 3] = G[p][a * 4 + 3] + g0 * t0 + g1 * t1 + g2 * t2;
      }
    }
  }
  __syncthreads();
  if (tid < NJ) {
    for (int a = 0; a < 3; ++a) {
      float corr = G[tid][a * 4 + 0] * J[tid][0] + G[tid][a * 4 + 1] * J[tid][1] +
                   G[tid][a * 4 + 2] * J[tid][2];
      rel[tid * 12 + a * 4 + 0] = G[tid][a * 4 + 0];
      rel[tid * 12 + a * 4 + 1] = G[tid][a * 4 + 1];
      rel[tid * 12 + a * 4 + 2] = G[tid][a * 4 + 2];
      rel[tid * 12 + a * 4 + 3] = G[tid][a * 4 + 3] - corr;
    }
  }
}

// ---------------------------------------------------------------------------
// K4a: pose blend. Block = 256 threads owns 16 vertices (one contiguous,
// 16B-aligned 39744B slab). Phase A: pure float4 coalesced stream -> LDS.
// Phase B: 16 threads per vertex dot 3x207 from LDS, shfl_xor reduce,
// sub==0 lane does vbuf[v] += delta (vbuf = v_shaped).
// ---------------------------------------------------------------------------
__global__ __launch_bounds__(256) void k_pose(
    const float* __restrict__ posedirs, const float* __restrict__ lrot,
    float* __restrict__ vbuf) {
  __shared__ float tile[TILEF];
  __shared__ float lr[NP];
  int tid = threadIdx.x;
  if (tid < NP) lr[tid] = lrot[tid];
  const float4* src = (const float4*)posedirs + (size_t)blockIdx.x * TILE4;
  float4* dst4 = (float4*)tile;
  #pragma unroll
  for (int it = 0; it < 10; ++it) {
    int i4 = tid + 256 * it;
    if (i4 < TILE4) dst4[i4] = src[i4];
  }
  __syncthreads();
  int lv = tid >> 4, sub = tid & 15;
  const float* row = tile + lv * ROWF;
  float a0 = 0.f, a1 = 0.f, a2 = 0.f;
  #pragma unroll
  for (int e = 0; e < 13; ++e) {
    int p = sub + 16 * e;
    if (p < NP) {
      float l = lr[p];
      a0 += row[p] * l;
      a1 += row[NP + p] * l;
      a2 += row[2 * NP + p] * l;
    }
  }
  #pragma unroll
  for (int off = 8; off > 0; off >>= 1) {
    a0 += __shfl_xor(a0, off);
    a1 += __shfl_xor(a1, off);
    a2 += __shfl_xor(a2, off);
  }
  if (sub == 0) {
    int v = blockIdx.x * VPB + lv;
    vbuf[3 * v + 0] += a0;
    vbuf[3 * v + 1] += a1;
    vbuf[3 * v + 2] += a2;
  }
}

// ---------------------------------------------------------------------------
// K4b: LBS + scale/trans. weights via float4, rel broadcast from LDS.
// ---------------------------------------------------------------------------
__global__ __launch_bounds__(256) void k_lbs2(
    const float* __restrict__ weights, const float* __restrict__ rel,
    const float* __restrict__ scale, const float* __restrict__ trans,
    float* __restrict__ vbuf) {
  __shared__ float rl[NJ * 12];
  int tid = threadIdx.x;
  for (int i = tid; i < NJ * 12; i += 256) rl[i] = rel[i];
  __syncthreads();
  int v = blockIdx.x * 256 + tid;
  if (v >= NV) return;
  float a0 = vbuf[v * 3 + 0], a1 = vbuf[v * 3 + 1], a2 = vbuf[v * 3 + 2];
  float4 w4[6];
  const float4* wv = (const float4*)(weights + (size_t)v * NJ);
  #pragma unroll
  for (int i = 0; i < 6; ++i) w4[i] = wv[i];
  const float* w = (const float*)w4;
  float T[12];
  #pragma unroll
  for (int e = 0; e < 12; ++e) T[e] = 0.f;
  #pragma unroll
  for (int j = 0; j < NJ; ++j) {
    float wj = w[j];
    #pragma unroll
    for (int e = 0; e < 12; ++e) T[e] += wj * rl[j * 12 + e];
  }
  float sc = scale[0];
  float o0 = T[0] * a0 + T[1] * a1 + T[2]  * a2 + T[3];
  float o1 = T[4] * a0 + T[5] * a1 + T[6]  * a2 + T[7];
  float o2 = T[8] * a0 + T[9] * a1 + T[10] * a2 + T[11];
  vbuf[v * 3 + 0] = o0 * sc + trans[0];
  vbuf[v * 3 + 1] = o1 * sc + trans[1];
  vbuf[v * 3 + 2] = o2 * sc + trans[2];
}

extern "C" void kernel_launch(void* const* d_in, const int* in_sizes, int n_in,
                              void* d_out, int out_size, void* d_ws, size_t ws_size,
                              hipStream_t stream) {
  const float* betas      = (const float*)d_in[0];
  const float* pose       = (const float*)d_in[1];
  const float* scale      = (const float*)d_in[2];
  const float* trans      = (const float*)d_in[3];
  const float* v_template = (const float*)d_in[4];
  const float* shapedirs  = (const float*)d_in[5];
  const float* posedirs   = (const float*)d_in[6];
  const float* Jreg       = (const float*)d_in[7];
  const float* weights    = (const float*)d_in[8];
  float* out = (float*)d_out;
  float* ws  = (float*)d_ws;

  float* jpart = ws;                       // NPART*24*3 = 1152 floats
  float* lrot  = ws + NPART * NJ * 3;      // 207 floats
  float* rel   = lrot + 256;               // 288 floats

  k_shape<<<(3 * NV + 255) / 256, 256, 0, stream>>>(betas, v_template, shapedirs, out);
  k_jreg<<<dim3(NJ, NPART), 256, 0, stream>>>(Jreg, out, jpart);
  k_fk<<<1, 64, 0, stream>>>(pose, jpart, lrot, rel);
  k_pose<<<NV / VPB, 256, 0, stream>>>(posedirs, lrot, out);
  k_lbs2<<<(NV + 255) / 256, 256, 0, stream>>>(weights, rel, scale, trans, out);
}